// Round 1
// baseline (671.961 us; speedup 1.0000x reference)
//
#include <hip/hip_runtime.h>
#include <stdint.h>

#define D_IN 128
#define D_H  256
#define BM   64

typedef float f32x4 __attribute__((ext_vector_type(4)));
typedef short s16x8 __attribute__((ext_vector_type(8)));

__device__ __forceinline__ unsigned short f2bf(float x) {
  union { float f; uint32_t u; } v; v.f = x;
  uint32_t r = v.u + 0x7fffu + ((v.u >> 16) & 1u);   // RNE
  return (unsigned short)(r >> 16);
}

// ---------------- prep: zero pooled accumulator, cast/transpose weights ----------------
__global__ void prep_kernel(const float* __restrict__ W1, const float* __restrict__ W2,
                            const float* __restrict__ Wg1,
                            float* __restrict__ pooled, unsigned short* __restrict__ W1t,
                            unsigned short* __restrict__ W2t, unsigned short* __restrict__ Wg1t,
                            int pooled_n) {
  int stride = gridDim.x * blockDim.x;
  int tid = blockIdx.x * blockDim.x + threadIdx.x;
  for (int i = tid; i < pooled_n; i += stride) pooled[i] = 0.0f;
  // W1t[n][k] = W1[k][n]  (out-feature-major, contiguous k for MFMA frags)
  for (int i = tid; i < D_H * D_IN; i += stride) {
    int n = i >> 7, k = i & (D_IN - 1);
    W1t[i] = f2bf(W1[k * D_H + n]);
  }
  for (int i = tid; i < D_H * D_H; i += stride) {
    int n = i >> 8, k = i & (D_H - 1);
    W2t[i]  = f2bf(W2[k * D_H + n]);
    Wg1t[i] = f2bf(Wg1[k * D_H + n]);
  }
}

// ---------------- node MLP + fused segment-sum ----------------
// Computes x^T = W^T @ h^T so that MFMA C-frag regs (4 consecutive rows = features,
// same col = node) map to contiguous [node][feature] LDS writes.
union NodeSmem {
  struct {
    unsigned short hA[BM][D_IN + 8];   // [64][136] bf16, padded: 2-way bank alias only
    unsigned short x1[BM][D_H + 8];    // [64][264] bf16
  } s;                                  // 51200 B
  float x2[BM][D_H + 4];               // [64][260] fp32 = 66560 B (aliases, used after sync)
};

__global__ __launch_bounds__(256, 2)
void node_kernel(const float* __restrict__ h, const int* __restrict__ gids,
                 const float* __restrict__ b1, const float* __restrict__ b2,
                 const unsigned short* __restrict__ W1t, const unsigned short* __restrict__ W2t,
                 float* __restrict__ pooled, int nnodes) {
  __shared__ NodeSmem sm;
  __shared__ int sgid[BM];
  const int tid  = threadIdx.x;
  const int lane = tid & 63;
  const int wave = tid >> 6;
  const int lr   = lane & 15;   // row-in-16 (A) / col-in-16 (B,C)
  const int q    = lane >> 4;   // quad
  const int row0 = blockIdx.x * BM;

  // stage h tile (fp32 -> bf16) into LDS, row-major [node][k]
  #pragma unroll
  for (int i = 0; i < 8; ++i) {
    int f4 = tid + i * 256;       // 2048 float4s = 64 rows x 32
    int r  = f4 >> 5;
    int c4 = f4 & 31;
    int gr = row0 + r;
    float4 v = make_float4(0.f, 0.f, 0.f, 0.f);
    if (gr < nnodes) v = ((const float4*)h)[gr * 32 + c4];
    uint32_t p0 = f2bf(v.x) | ((uint32_t)f2bf(v.y) << 16);
    uint32_t p1 = f2bf(v.z) | ((uint32_t)f2bf(v.w) << 16);
    uint32_t* dst = (uint32_t*)&sm.s.hA[r][c4 * 4];
    dst[0] = p0; dst[1] = p1;
  }
  if (tid < BM) {
    int gr = row0 + tid;
    sgid[tid] = (gr < nnodes) ? gids[gr] : -1;   // -1 rows excluded from pooling
  }
  __syncthreads();

  f32x4 acc[4][4];

  // ---- layer 1: x1^T = W1^T(A, 256x128) @ h^T(B, 128x64) ----
  #pragma unroll
  for (int mt = 0; mt < 4; ++mt)
    #pragma unroll
    for (int nt = 0; nt < 4; ++nt)
      acc[mt][nt] = (f32x4){0.f, 0.f, 0.f, 0.f};

  #pragma unroll
  for (int kk = 0; kk < D_IN; kk += 32) {
    const int kq = kk + q * 8;
    s16x8 a[4], b[4];
    #pragma unroll
    for (int mt = 0; mt < 4; ++mt) {
      int f = wave * 64 + mt * 16 + lr;                 // out-feature
      a[mt] = *(const s16x8*)&W1t[f * D_IN + kq];       // L2-resident, 16B/lane
    }
    #pragma unroll
    for (int nt = 0; nt < 4; ++nt)
      b[nt] = *(const s16x8*)&sm.s.hA[nt * 16 + lr][kq]; // ds_read_b128
    #pragma unroll
    for (int mt = 0; mt < 4; ++mt)
      #pragma unroll
      for (int nt = 0; nt < 4; ++nt)
        acc[mt][nt] = __builtin_amdgcn_mfma_f32_16x16x32_bf16(a[mt], b[nt], acc[mt][nt], 0, 0, 0);
  }

  // epilogue 1: relu(+b1) -> x1 LDS bf16 [node][feature]; C regs = 4 consecutive features
  #pragma unroll
  for (int mt = 0; mt < 4; ++mt) {
    int f = wave * 64 + mt * 16 + q * 4;
    float4 bias = *(const float4*)&b1[f];
    #pragma unroll
    for (int nt = 0; nt < 4; ++nt) {
      int nd = nt * 16 + lr;
      float v0 = fmaxf(acc[mt][nt][0] + bias.x, 0.f);
      float v1 = fmaxf(acc[mt][nt][1] + bias.y, 0.f);
      float v2 = fmaxf(acc[mt][nt][2] + bias.z, 0.f);
      float v3 = fmaxf(acc[mt][nt][3] + bias.w, 0.f);
      uint32_t p0 = f2bf(v0) | ((uint32_t)f2bf(v1) << 16);
      uint32_t p1 = f2bf(v2) | ((uint32_t)f2bf(v3) << 16);
      uint32_t* dst = (uint32_t*)&sm.s.x1[nd][f];
      dst[0] = p0; dst[1] = p1;
    }
  }
  __syncthreads();

  // ---- layer 2: x2^T = W2^T(A, 256x256) @ x1^T(B, 256x64) ----
  #pragma unroll
  for (int mt = 0; mt < 4; ++mt)
    #pragma unroll
    for (int nt = 0; nt < 4; ++nt)
      acc[mt][nt] = (f32x4){0.f, 0.f, 0.f, 0.f};

  #pragma unroll
  for (int kk = 0; kk < D_H; kk += 32) {
    const int kq = kk + q * 8;
    s16x8 a[4], b[4];
    #pragma unroll
    for (int mt = 0; mt < 4; ++mt) {
      int f = wave * 64 + mt * 16 + lr;
      a[mt] = *(const s16x8*)&W2t[f * D_H + kq];
    }
    #pragma unroll
    for (int nt = 0; nt < 4; ++nt)
      b[nt] = *(const s16x8*)&sm.s.x1[nt * 16 + lr][kq];
    #pragma unroll
    for (int mt = 0; mt < 4; ++mt)
      #pragma unroll
      for (int nt = 0; nt < 4; ++nt)
        acc[mt][nt] = __builtin_amdgcn_mfma_f32_16x16x32_bf16(a[mt], b[nt], acc[mt][nt], 0, 0, 0);
  }
  __syncthreads();   // all x1/hA reads done; union region may be overwritten with x2

  // epilogue 2: relu(+b2) -> x2 fp32 LDS [node][feature]
  #pragma unroll
  for (int mt = 0; mt < 4; ++mt) {
    int f = wave * 64 + mt * 16 + q * 4;
    float4 bias = *(const float4*)&b2[f];
    #pragma unroll
    for (int nt = 0; nt < 4; ++nt) {
      int nd = nt * 16 + lr;
      f32x4 v;
      v[0] = fmaxf(acc[mt][nt][0] + bias.x, 0.f);
      v[1] = fmaxf(acc[mt][nt][1] + bias.y, 0.f);
      v[2] = fmaxf(acc[mt][nt][2] + bias.z, 0.f);
      v[3] = fmaxf(acc[mt][nt][3] + bias.w, 0.f);
      *(f32x4*)&sm.x2[nd][f] = v;   // ds_write_b128
    }
  }
  __syncthreads();

  // fused segment-sum: graph_ids sorted -> run detection, one atomic per (run, feature)
  float racc = 0.f;
  for (int r = 0; r < BM; ++r) {
    int g = sgid[r];                    // wave-uniform
    if (g >= 0) {
      racc += sm.x2[r][tid];
      if (r == BM - 1 || sgid[r + 1] != g) {
        atomicAdd(&pooled[g * D_H + tid], racc);
        racc = 0.f;
      }
    }
  }
}

// ---------------- graph MLP ----------------
union GraphSmem {
  unsigned short pA[BM][D_H + 8];   // pooled bf16 [graph][feature] 33792 B
  float y[BM][D_H + 4];             // y fp32, 66560 B (aliases after sync)
};

__global__ __launch_bounds__(256, 2)
void graph_kernel(const float* __restrict__ pooled, const float* __restrict__ bg1,
                  const unsigned short* __restrict__ Wg1t, const float* __restrict__ Wg2,
                  const float* __restrict__ bg2, float* __restrict__ out, int ngraphs) {
  __shared__ GraphSmem sm;
  const int tid  = threadIdx.x;
  const int lane = tid & 63;
  const int wave = tid >> 6;
  const int lr   = lane & 15;
  const int q    = lane >> 4;
  const int g0   = blockIdx.x * BM;

  // stage pooled (fp32 -> bf16)
  #pragma unroll
  for (int i = 0; i < 16; ++i) {
    int f4 = tid + i * 256;        // 4096 float4s = 64 rows x 64
    int r  = f4 >> 6;
    int c4 = f4 & 63;
    float4 v = make_float4(0.f, 0.f, 0.f, 0.f);
    if (g0 + r < ngraphs) v = ((const float4*)pooled)[(size_t)(g0 + r) * 64 + c4];
    uint32_t p0 = f2bf(v.x) | ((uint32_t)f2bf(v.y) << 16);
    uint32_t p1 = f2bf(v.z) | ((uint32_t)f2bf(v.w) << 16);
    uint32_t* dst = (uint32_t*)&sm.pA[r][c4 * 4];
    dst[0] = p0; dst[1] = p1;
  }
  __syncthreads();

  f32x4 acc[4][4];
  #pragma unroll
  for (int mt = 0; mt < 4; ++mt)
    #pragma unroll
    for (int nt = 0; nt < 4; ++nt)
      acc[mt][nt] = (f32x4){0.f, 0.f, 0.f, 0.f};

  #pragma unroll
  for (int kk = 0; kk < D_H; kk += 32) {
    const int kq = kk + q * 8;
    s16x8 a[4], b[4];
    #pragma unroll
    for (int mt = 0; mt < 4; ++mt) {
      int f = wave * 64 + mt * 16 + lr;
      a[mt] = *(const s16x8*)&Wg1t[f * D_H + kq];
    }
    #pragma unroll
    for (int nt = 0; nt < 4; ++nt)
      b[nt] = *(const s16x8*)&sm.pA[nt * 16 + lr][kq];
    #pragma unroll
    for (int mt = 0; mt < 4; ++mt)
      #pragma unroll
      for (int nt = 0; nt < 4; ++nt)
        acc[mt][nt] = __builtin_amdgcn_mfma_f32_16x16x32_bf16(a[mt], b[nt], acc[mt][nt], 0, 0, 0);
  }
  __syncthreads();

  #pragma unroll
  for (int mt = 0; mt < 4; ++mt) {
    int f = wave * 64 + mt * 16 + q * 4;
    float4 bias = *(const float4*)&bg1[f];
    #pragma unroll
    for (int nt = 0; nt < 4; ++nt) {
      int nd = nt * 16 + lr;
      f32x4 v;
      v[0] = fmaxf(acc[mt][nt][0] + bias.x, 0.f);
      v[1] = fmaxf(acc[mt][nt][1] + bias.y, 0.f);
      v[2] = fmaxf(acc[mt][nt][2] + bias.z, 0.f);
      v[3] = fmaxf(acc[mt][nt][3] + bias.w, 0.f);
      *(f32x4*)&sm.y[nd][f] = v;
    }
  }
  __syncthreads();

  // out[g] = y[g,:] . Wg2 + bg2 ; 4 threads per graph, f = part + 4*i keeps banks spread
  int gloc = tid >> 2;
  int part = tid & 3;
  float p = 0.f;
  #pragma unroll 8
  for (int i = 0; i < 64; ++i) {
    int f = part + 4 * i;
    p += sm.y[gloc][f] * Wg2[f];
  }
  p += __shfl_xor(p, 1);
  p += __shfl_xor(p, 2);
  if (part == 0 && (g0 + gloc) < ngraphs)
    out[g0 + gloc] = p + bg2[0];
}

extern "C" void kernel_launch(void* const* d_in, const int* in_sizes, int n_in,
                              void* d_out, int out_size, void* d_ws, size_t ws_size,
                              hipStream_t stream) {
  const float* h   = (const float*)d_in[0];
  const int*   gid = (const int*)d_in[1];
  // d_in[2] = num_graphs (device scalar) — G taken from out_size instead
  const float* W1  = (const float*)d_in[3];
  const float* b1  = (const float*)d_in[4];
  const float* W2  = (const float*)d_in[5];
  const float* b2  = (const float*)d_in[6];
  const float* Wg1 = (const float*)d_in[7];
  const float* bg1 = (const float*)d_in[8];
  const float* Wg2 = (const float*)d_in[9];
  const float* bg2 = (const float*)d_in[10];
  float* out = (float*)d_out;

  const int N = in_sizes[1];
  const int G = out_size;

  // workspace layout (d_ws is re-poisoned every launch; prep re-initializes it)
  char* ws = (char*)d_ws;
  float* pooled = (float*)ws;                                   // G*256*4 = 20.48 MB
  size_t off = (size_t)G * D_H * sizeof(float);
  unsigned short* W1t  = (unsigned short*)(ws + off); off += (size_t)D_H * D_IN * 2;
  unsigned short* W2t  = (unsigned short*)(ws + off); off += (size_t)D_H * D_H * 2;
  unsigned short* Wg1t = (unsigned short*)(ws + off);

  prep_kernel<<<512, 256, 0, stream>>>(W1, W2, Wg1, pooled, W1t, W2t, Wg1t, G * D_H);
  node_kernel<<<(N + BM - 1) / BM, 256, 0, stream>>>(h, gid, b1, b2, W1t, W2t, pooled, N);
  graph_kernel<<<(G + BM - 1) / BM, 256, 0, stream>>>(pooled, bg1, Wg1t, Wg2, bg2, out, G);
}

// Round 2
// 579.330 us; speedup vs baseline: 1.1599x; 1.1599x over previous
//
#include <hip/hip_runtime.h>
#include <stdint.h>

#define D_IN 128
#define D_H  256
#define BM   64

typedef float f32x4 __attribute__((ext_vector_type(4)));
typedef short s16x8 __attribute__((ext_vector_type(8)));
typedef unsigned int u32x2 __attribute__((ext_vector_type(2)));
typedef unsigned int u32x4 __attribute__((ext_vector_type(4)));

__device__ __forceinline__ unsigned short f2bf(float x) {
  union { float f; uint32_t u; } v; v.f = x;
  uint32_t r = v.u + 0x7fffu + ((v.u >> 16) & 1u);   // RNE
  return (unsigned short)(r >> 16);
}
__device__ __forceinline__ float bf2f(unsigned short u) {
  union { uint32_t u; float f; } v; v.u = (uint32_t)u << 16;
  return v.f;
}

// ---------------- prep: zero pooled accumulator, cast/transpose weights ----------------
__global__ void prep_kernel(const float* __restrict__ W1, const float* __restrict__ W2,
                            const float* __restrict__ Wg1,
                            float* __restrict__ pooled, unsigned short* __restrict__ W1t,
                            unsigned short* __restrict__ W2t, unsigned short* __restrict__ Wg1t,
                            int pooled_n) {
  int stride = gridDim.x * blockDim.x;
  int tid = blockIdx.x * blockDim.x + threadIdx.x;
  for (int i = tid; i < pooled_n; i += stride) pooled[i] = 0.0f;
  // W1t[n][k] = W1[k][n]  (out-feature-major, contiguous k for MFMA frags)
  for (int i = tid; i < D_H * D_IN; i += stride) {
    int n = i >> 7, k = i & (D_IN - 1);
    W1t[i] = f2bf(W1[k * D_H + n]);
  }
  for (int i = tid; i < D_H * D_H; i += stride) {
    int n = i >> 8, k = i & (D_H - 1);
    W2t[i]  = f2bf(W2[k * D_H + n]);
    Wg1t[i] = f2bf(Wg1[k * D_H + n]);
  }
}

// ---------------- node MLP + fused segment-sum ----------------
// XOR-swizzled LDS tiles (granule16 ^= row&7): unpadded rows (stride 128/256
// half = 0 mod 32 banks) become conflict-free for b128 reads (8-way = the
// 8-cycle floor for 64x16B) and for the b64 epilogue writes.
// x2 (post-layer-2 activations) is stored bf16 reusing the x1 tile -> LDS
// footprint 48.25 KB -> 3 blocks/CU.

__global__ __launch_bounds__(256, 3)
void node_kernel(const float* __restrict__ h, const int* __restrict__ gids,
                 const float* __restrict__ b1, const float* __restrict__ b2,
                 const unsigned short* __restrict__ W1t, const unsigned short* __restrict__ W2t,
                 float* __restrict__ pooled, int nnodes) {
  __shared__ unsigned short hA[BM * D_IN];   // 16 KB, swizzled [row][k]
  __shared__ unsigned short x1s[BM * D_H];   // 32 KB, swizzled [row][f]; reused for x2
  __shared__ int sgid[BM];
  const int tid  = threadIdx.x;
  const int lane = tid & 63;
  const int wave = tid >> 6;
  const int lr   = lane & 15;   // row-in-16 (A) / col-in-16 (B,C)
  const int q    = lane >> 4;   // quad
  const int row0 = blockIdx.x * BM;

  // ---- preload ALL layer-1 A-frags (64 VGPRs) so L2 latency hides behind staging+barrier
  s16x8 a[4][4];
  #pragma unroll
  for (int ks = 0; ks < 4; ++ks)
    #pragma unroll
    for (int mt = 0; mt < 4; ++mt)
      a[ks][mt] = *(const s16x8*)&W1t[(wave * 64 + mt * 16 + lr) * D_IN + ks * 32 + q * 8];

  if (tid < BM) {
    int gr = row0 + tid;
    sgid[tid] = (gr < nnodes) ? gids[gr] : -1;   // -1 rows excluded from pooling
  }

  // ---- stage h tile (fp32 -> bf16) into swizzled LDS; one 16B granule per thread/iter
  #pragma unroll
  for (int i = 0; i < 4; ++i) {
    int gi = tid + i * 256;            // granule id: 64 rows x 16 granules
    int r  = gi >> 4;
    int gc = gi & 15;
    int gr = row0 + r;
    f32x4 v0 = (f32x4){0.f, 0.f, 0.f, 0.f}, v1 = v0;
    if (gr < nnodes) {
      const f32x4* p = (const f32x4*)(h + (size_t)gr * D_IN + gc * 8);
      v0 = __builtin_nontemporal_load(p);       // h is read-once: don't pollute L2
      v1 = __builtin_nontemporal_load(p + 1);
    }
    u32x4 u;
    u[0] = f2bf(v0[0]) | ((uint32_t)f2bf(v0[1]) << 16);
    u[1] = f2bf(v0[2]) | ((uint32_t)f2bf(v0[3]) << 16);
    u[2] = f2bf(v1[0]) | ((uint32_t)f2bf(v1[1]) << 16);
    u[3] = f2bf(v1[2]) | ((uint32_t)f2bf(v1[3]) << 16);
    *(u32x4*)&hA[r * D_IN + ((gc ^ (r & 7)) << 3)] = u;
  }
  __syncthreads();

  f32x4 acc[4][4];
  #pragma unroll
  for (int mt = 0; mt < 4; ++mt)
    #pragma unroll
    for (int nt = 0; nt < 4; ++nt)
      acc[mt][nt] = (f32x4){0.f, 0.f, 0.f, 0.f};

  // ---- layer 1: x1^T = W1^T(A, 256x128) @ h^T(B, 128x64) ----
  #pragma unroll
  for (int ks = 0; ks < 4; ++ks) {
    const int kq = ks * 32 + q * 8;
    s16x8 b[4];
    #pragma unroll
    for (int nt = 0; nt < 4; ++nt)
      b[nt] = *(const s16x8*)&hA[(nt * 16 + lr) * D_IN + (((kq >> 3) ^ (lr & 7)) << 3)];
    #pragma unroll
    for (int mt = 0; mt < 4; ++mt)
      #pragma unroll
      for (int nt = 0; nt < 4; ++nt)
        acc[mt][nt] = __builtin_amdgcn_mfma_f32_16x16x32_bf16(a[ks][mt], b[nt], acc[mt][nt], 0, 0, 0);
  }

  // epilogue 1: relu(+b1) -> x1 bf16 swizzled; b64 writes, conflict-free
  #pragma unroll
  for (int mt = 0; mt < 4; ++mt) {
    int f = wave * 64 + mt * 16 + q * 4;
    float4 bias = *(const float4*)&b1[f];
    #pragma unroll
    for (int nt = 0; nt < 4; ++nt) {
      int nd = nt * 16 + lr;
      uint32_t p0 = f2bf(fmaxf(acc[mt][nt][0] + bias.x, 0.f)) |
                    ((uint32_t)f2bf(fmaxf(acc[mt][nt][1] + bias.y, 0.f)) << 16);
      uint32_t p1 = f2bf(fmaxf(acc[mt][nt][2] + bias.z, 0.f)) |
                    ((uint32_t)f2bf(fmaxf(acc[mt][nt][3] + bias.w, 0.f)) << 16);
      u32x2 w = {p0, p1};
      *(u32x2*)&x1s[nd * D_H + (((f >> 3) ^ (nd & 7)) << 3) + (f & 7)] = w;
    }
  }

  // ---- preload layer-2 A half 0 (k=0..127) BEFORE the barrier: latency overlaps barrier wait
  #pragma unroll
  for (int ks = 0; ks < 4; ++ks)
    #pragma unroll
    for (int mt = 0; mt < 4; ++mt)
      a[ks][mt] = *(const s16x8*)&W2t[(wave * 64 + mt * 16 + lr) * D_H + ks * 32 + q * 8];
  __syncthreads();

  #pragma unroll
  for (int mt = 0; mt < 4; ++mt)
    #pragma unroll
    for (int nt = 0; nt < 4; ++nt)
      acc[mt][nt] = (f32x4){0.f, 0.f, 0.f, 0.f};

  // ---- layer 2 half 0
  #pragma unroll
  for (int ks = 0; ks < 4; ++ks) {
    const int kq = ks * 32 + q * 8;
    s16x8 b[4];
    #pragma unroll
    for (int nt = 0; nt < 4; ++nt)
      b[nt] = *(const s16x8*)&x1s[(nt * 16 + lr) * D_H + (((kq >> 3) ^ (lr & 7)) << 3)];
    #pragma unroll
    for (int mt = 0; mt < 4; ++mt)
      #pragma unroll
      for (int nt = 0; nt < 4; ++nt)
        acc[mt][nt] = __builtin_amdgcn_mfma_f32_16x16x32_bf16(a[ks][mt], b[nt], acc[mt][nt], 0, 0, 0);
  }
  // ---- layer 2 half 1 (reload A into the same 64 regs)
  #pragma unroll
  for (int ks = 0; ks < 4; ++ks)
    #pragma unroll
    for (int mt = 0; mt < 4; ++mt)
      a[ks][mt] = *(const s16x8*)&W2t[(wave * 64 + mt * 16 + lr) * D_H + 128 + ks * 32 + q * 8];
  #pragma unroll
  for (int ks = 0; ks < 4; ++ks) {
    const int kq = 128 + ks * 32 + q * 8;
    s16x8 b[4];
    #pragma unroll
    for (int nt = 0; nt < 4; ++nt)
      b[nt] = *(const s16x8*)&x1s[(nt * 16 + lr) * D_H + (((kq >> 3) ^ (lr & 7)) << 3)];
    #pragma unroll
    for (int mt = 0; mt < 4; ++mt)
      #pragma unroll
      for (int nt = 0; nt < 4; ++nt)
        acc[mt][nt] = __builtin_amdgcn_mfma_f32_16x16x32_bf16(a[ks][mt], b[nt], acc[mt][nt], 0, 0, 0);
  }
  __syncthreads();   // all x1 reads done; x1s may be overwritten with x2

  // epilogue 2: relu(+b2) -> x2 bf16 into x1s (swizzled)
  #pragma unroll
  for (int mt = 0; mt < 4; ++mt) {
    int f = wave * 64 + mt * 16 + q * 4;
    float4 bias = *(const float4*)&b2[f];
    #pragma unroll
    for (int nt = 0; nt < 4; ++nt) {
      int nd = nt * 16 + lr;
      uint32_t p0 = f2bf(fmaxf(acc[mt][nt][0] + bias.x, 0.f)) |
                    ((uint32_t)f2bf(fmaxf(acc[mt][nt][1] + bias.y, 0.f)) << 16);
      uint32_t p1 = f2bf(fmaxf(acc[mt][nt][2] + bias.z, 0.f)) |
                    ((uint32_t)f2bf(fmaxf(acc[mt][nt][3] + bias.w, 0.f)) << 16);
      u32x2 w = {p0, p1};
      *(u32x2*)&x1s[nd * D_H + (((f >> 3) ^ (nd & 7)) << 3) + (f & 7)] = w;
    }
  }
  __syncthreads();

  // fused segment-sum: graph_ids sorted -> run detection, one atomic per (run, feature)
  float racc = 0.f;
  for (int r = 0; r < BM; ++r) {
    int g = sgid[r];                    // wave-uniform
    if (g >= 0) {
      racc += bf2f(x1s[r * D_H + (((tid >> 3) ^ (r & 7)) << 3) + (tid & 7)]);
      if (r == BM - 1 || sgid[r + 1] != g) {
        atomicAdd(&pooled[g * D_H + tid], racc);
        racc = 0.f;
      }
    }
  }
}

// ---------------- graph MLP (unchanged from round 0) ----------------
union GraphSmem {
  unsigned short pA[BM][D_H + 8];   // pooled bf16 [graph][feature]
  float y[BM][D_H + 4];             // y fp32 (aliases after sync)
};

__global__ __launch_bounds__(256, 2)
void graph_kernel(const float* __restrict__ pooled, const float* __restrict__ bg1,
                  const unsigned short* __restrict__ Wg1t, const float* __restrict__ Wg2,
                  const float* __restrict__ bg2, float* __restrict__ out, int ngraphs) {
  __shared__ GraphSmem sm;
  const int tid  = threadIdx.x;
  const int lane = tid & 63;
  const int wave = tid >> 6;
  const int lr   = lane & 15;
  const int q    = lane >> 4;
  const int g0   = blockIdx.x * BM;

  #pragma unroll
  for (int i = 0; i < 16; ++i) {
    int f4 = tid + i * 256;
    int r  = f4 >> 6;
    int c4 = f4 & 63;
    float4 v = make_float4(0.f, 0.f, 0.f, 0.f);
    if (g0 + r < ngraphs) v = ((const float4*)pooled)[(size_t)(g0 + r) * 64 + c4];
    uint32_t p0 = f2bf(v.x) | ((uint32_t)f2bf(v.y) << 16);
    uint32_t p1 = f2bf(v.z) | ((uint32_t)f2bf(v.w) << 16);
    uint32_t* dst = (uint32_t*)&sm.pA[r][c4 * 4];
    dst[0] = p0; dst[1] = p1;
  }
  __syncthreads();

  f32x4 acc[4][4];
  #pragma unroll
  for (int mt = 0; mt < 4; ++mt)
    #pragma unroll
    for (int nt = 0; nt < 4; ++nt)
      acc[mt][nt] = (f32x4){0.f, 0.f, 0.f, 0.f};

  #pragma unroll
  for (int kk = 0; kk < D_H; kk += 32) {
    const int kq = kk + q * 8;
    s16x8 a[4], b[4];
    #pragma unroll
    for (int mt = 0; mt < 4; ++mt) {
      int f = wave * 64 + mt * 16 + lr;
      a[mt] = *(const s16x8*)&Wg1t[f * D_H + kq];
    }
    #pragma unroll
    for (int nt = 0; nt < 4; ++nt)
      b[nt] = *(const s16x8*)&sm.pA[nt * 16 + lr][kq];
    #pragma unroll
    for (int mt = 0; mt < 4; ++mt)
      #pragma unroll
      for (int nt = 0; nt < 4; ++nt)
        acc[mt][nt] = __builtin_amdgcn_mfma_f32_16x16x32_bf16(a[mt], b[nt], acc[mt][nt], 0, 0, 0);
  }
  __syncthreads();

  #pragma unroll
  for (int mt = 0; mt < 4; ++mt) {
    int f = wave * 64 + mt * 16 + q * 4;
    float4 bias = *(const float4*)&bg1[f];
    #pragma unroll
    for (int nt = 0; nt < 4; ++nt) {
      int nd = nt * 16 + lr;
      f32x4 v;
      v[0] = fmaxf(acc[mt][nt][0] + bias.x, 0.f);
      v[1] = fmaxf(acc[mt][nt][1] + bias.y, 0.f);
      v[2] = fmaxf(acc[mt][nt][2] + bias.z, 0.f);
      v[3] = fmaxf(acc[mt][nt][3] + bias.w, 0.f);
      *(f32x4*)&sm.y[nd][f] = v;
    }
  }
  __syncthreads();

  int gloc = tid >> 2;
  int part = tid & 3;
  float p = 0.f;
  #pragma unroll 8
  for (int i = 0; i < 64; ++i) {
    int f = part + 4 * i;
    p += sm.y[gloc][f] * Wg2[f];
  }
  p += __shfl_xor(p, 1);
  p += __shfl_xor(p, 2);
  if (part == 0 && (g0 + gloc) < ngraphs)
    out[g0 + gloc] = p + bg2[0];
}

extern "C" void kernel_launch(void* const* d_in, const int* in_sizes, int n_in,
                              void* d_out, int out_size, void* d_ws, size_t ws_size,
                              hipStream_t stream) {
  const float* h   = (const float*)d_in[0];
  const int*   gid = (const int*)d_in[1];
  const float* W1  = (const float*)d_in[3];
  const float* b1  = (const float*)d_in[4];
  const float* W2  = (const float*)d_in[5];
  const float* b2  = (const float*)d_in[6];
  const float* Wg1 = (const float*)d_in[7];
  const float* bg1 = (const float*)d_in[8];
  const float* Wg2 = (const float*)d_in[9];
  const float* bg2 = (const float*)d_in[10];
  float* out = (float*)d_out;

  const int N = in_sizes[1];
  const int G = out_size;

  char* ws = (char*)d_ws;
  float* pooled = (float*)ws;                                   // G*256*4 = 20.48 MB
  size_t off = (size_t)G * D_H * sizeof(float);
  unsigned short* W1t  = (unsigned short*)(ws + off); off += (size_t)D_H * D_IN * 2;
  unsigned short* W2t  = (unsigned short*)(ws + off); off += (size_t)D_H * D_H * 2;
  unsigned short* Wg1t = (unsigned short*)(ws + off);

  prep_kernel<<<512, 256, 0, stream>>>(W1, W2, Wg1, pooled, W1t, W2t, Wg1t, G * D_H);
  node_kernel<<<(N + BM - 1) / BM, 256, 0, stream>>>(h, gid, b1, b2, W1t, W2t, pooled, N);
  graph_kernel<<<(G + BM - 1) / BM, 256, 0, stream>>>(pooled, bg1, Wg1t, Wg2, bg2, out, G);
}